// Round 10
// baseline (199.793 us; speedup 1.0000x reference)
//
#include <hip/hip_runtime.h>

#define NROWS   131072
#define DIM     64
#define K       1024
#define QOFF    1
#define IDXOFF  8388609        // 1 + NROWS*DIM
// Per-row routing margin in 2^-20 distance units: hard error of the fp16 screen
// is 2^-19 * sum|x_i| per distance => 2*S units.  mq = 2.002*S + 5 covers
// fp32 S-summation slack, MFMA fp32 accumulation (<=1), trunc quant (2), ceil (1).
#define NSCR    1024           // screen grid (128 rows/block, 4 blocks/CU)

typedef float    f32x4 __attribute__((ext_vector_type(4)));
typedef _Float16 f16x8 __attribute__((ext_vector_type(8)));

// ---------- np-exact arithmetic (validated: absmax 0.0) ----------
__device__ __forceinline__ float np_norm64(const float* v) {
    #pragma clang fp contract(off)
    float r[8];
    #pragma unroll
    for (int k = 0; k < 8; ++k) r[k] = v[k] * v[k];
    #pragma unroll
    for (int i = 8; i < 64; i += 8)
        #pragma unroll
        for (int k = 0; k < 8; ++k) r[k] += v[i + k] * v[i + k];
    return ((r[0] + r[1]) + (r[2] + r[3])) + ((r[4] + r[5]) + (r[6] + r[7]));
}
__device__ __forceinline__ float exact_dot64(const float* __restrict__ xr,
                                             const float* __restrict__ e) {
    float a0 = 0.f, a1 = 0.f, a2 = 0.f, a3 = 0.f;
    #pragma unroll
    for (int i = 0; i < 64; i += 4) {
        a0 = fmaf(xr[i + 0], e[i + 0], a0);
        a1 = fmaf(xr[i + 1], e[i + 1], a1);
        a2 = fmaf(xr[i + 2], e[i + 2], a2);
        a3 = fmaf(xr[i + 3], e[i + 3], a3);
    }
    return (a0 + a1) + (a2 + a3);
}
__device__ __forceinline__ float exact_d(float cr, float sej, float dot) {
    #pragma clang fp contract(off)
    float t = cr + sej;
    return t - 2.0f * dot;
}

// ---------- prep: Gf (fp16 fragment-order), wT (column-major fp32), se/se20 ----------
__global__ void vq_prep(const float* __restrict__ w, unsigned short* __restrict__ Gf,
                        float* __restrict__ wT, float* __restrict__ se,
                        float* __restrict__ se20) {
    int gid = blockIdx.x * 256 + threadIdx.x;       // 0..8191 = ntile*128 + c*64 + lane
    int lane = gid & 63, c = (gid >> 6) & 1, ntile = gid >> 7;
    int code = ntile * 16 + (lane & 15);
    int k0 = c * 32 + (lane >> 4) * 8;
    const float* rowp = w + code * 64 + k0;
    f16x8 h8;
    #pragma unroll
    for (int j = 0; j < 8; ++j) h8[j] = (_Float16)(rowp[j] * 1024.0f);  // *1024 exact; RNE
    *(f16x8*)(Gf + gid * 8) = h8;                    // fully coalesced 16B store
    // transpose: wT[i*1024 + j] = w[j*64 + i]  (coalesced writes)
    #pragma unroll
    for (int t = 0; t < 8; ++t) {
        int flat = t * 8192 + gid;                   // 0..65535
        int i = flat >> 10, j = flat & 1023;
        wT[flat] = w[j * 64 + i];
    }
    if (gid < K) {
        #pragma clang fp contract(off)
        const float* e = w + gid * 64;
        float r[8];
        #pragma unroll
        for (int k2 = 0; k2 < 8; ++k2) r[k2] = e[k2] * e[k2];
        #pragma unroll
        for (int i = 8; i < 64; i += 8)
            #pragma unroll
            for (int k2 = 0; k2 < 8; ++k2) r[k2] += e[i + k2] * e[i + k2];
        float v = ((r[0] + r[1]) + (r[2] + r[3])) + ((r[4] + r[5]) + (r[6] + r[7]));
        se[gid] = v;
        se20[gid] = v * 1048576.0f;                 // exact (power of 2)
    }
}

// ---------- screen: fp16 MFMA scan + top-3 + IN-KERNEL exact resolution ----------
// block = 256 (4 waves); TWO 16-row m-tiles per wave (32 rows); grid = 1024 (4 blocks/CU).
// Undecided rows resolved in the epilogue: pairs thread-per-pair (np-exact compare),
// fulls wave-per-row (wT-coalesced np-exact rescan).  No second pass, no global lists.
__global__ __launch_bounds__(256, 4) void vq_screen(
    const float* __restrict__ x, const float* __restrict__ w,
    const unsigned short* __restrict__ Gf, const float* __restrict__ se20,
    const float* __restrict__ se, const float* __restrict__ wT,
    float* __restrict__ out, float* __restrict__ partial) {
    __shared__ float sSe[1024];         // 4 KB: se*2^20
    __shared__ float sPart[4];
    __shared__ int sCnt[2];
    __shared__ int sPairRow[128], sPairJJ[128], sFullRow[128];
    const int tid  = threadIdx.x;
    const int wave = tid >> 6, lane = tid & 63;
    const int quad = lane >> 4, m16 = lane & 15;
    const int wrow0 = blockIdx.x * 128 + wave * 32;

    if (tid < 2) sCnt[tid] = 0;
    #pragma unroll
    for (int t = 0; t < 4; ++t) sSe[t * 256 + tid] = se20[t * 256 + tid];

    // A fragments: fp16(x), A[m = m16][k = quad*8 + j], chunk c: k = 32c..32c+31
    f16x8 Ah[2][2];
    float Sloc[2] = {0.f, 0.f};
    #pragma unroll
    for (int mt = 0; mt < 2; ++mt)
        #pragma unroll
        for (int c = 0; c < 2; ++c) {
            const float* p = x + (wrow0 + mt * 16 + m16) * 64 + c * 32 + quad * 8;
            f32x4 u0 = *(const f32x4*)p;
            f32x4 u1 = *(const f32x4*)(p + 4);
            #pragma unroll
            for (int j = 0; j < 8; ++j) {
                float xv = (j < 4) ? u0[j] : u1[j - 4];
                Ah[mt][c][j] = (_Float16)xv;
                Sloc[mt] += fabsf(xv);
            }
        }
    #pragma unroll
    for (int mt = 0; mt < 2; ++mt) {
        Sloc[mt] += __shfl_xor(Sloc[mt], 16, 64);
        Sloc[mt] += __shfl_xor(Sloc[mt], 32, 64);   // every lane: S(row = its m16)
    }

    int m1[2][4], m2[2][4], m3[2][4];
    #pragma unroll
    for (int mt = 0; mt < 2; ++mt)
        #pragma unroll
        for (int r = 0; r < 4; ++r) {
            m1[mt][r] = 0x7fffffff; m2[mt][r] = 0x7fffffff; m3[mt][r] = 0x7fffffff;
        }

    __syncthreads();                    // sSe + sCnt ready

    #pragma unroll 8
    for (int t = 0; t < 64; ++t) {      // 64 code-tiles of 16
        f16x8 B0 = *(const f16x8*)(Gf + t * 1024 + lane * 8);        // chunk 0, coalesced
        f16x8 B1 = *(const f16x8*)(Gf + t * 1024 + 512 + lane * 8);  // chunk 1
        float sen = sSe[t * 16 + m16];
        int jn = t * 16 + m16;
        #pragma unroll
        for (int mt = 0; mt < 2; ++mt) {
            f32x4 acc = {0.f, 0.f, 0.f, 0.f};
            acc = __builtin_amdgcn_mfma_f32_16x16x32_f16(Ah[mt][0], B0, acc, 0, 0, 0);
            acc = __builtin_amdgcn_mfma_f32_16x16x32_f16(Ah[mt][1], B1, acc, 0, 0, 0);
            #pragma unroll
            for (int r = 0; r < 4; ++r) {
                // f*2^20 = se*2^20 - 2*2^-10*2^20*dot' ; dot' = 1024*x.e
                float kf = fmaf(acc[r], -2048.0f, sen);
                int q = (int)kf;                              // trunc: monotone
                int key = (int)((unsigned)q << 10) | jn;
                int a  = max(m2[mt][r], key);                 // old m2
                int t2 = max(m1[mt][r], key);                 // old m1
                m3[mt][r] = min(m3[mt][r], a);
                m2[mt][r] = min(m2[mt][r], t2);
                m1[mt][r] = min(m1[mt][r], key);
            }
        }
    }

    // butterfly all-reduce top-3 over the 16 cols (C layout: col=m16, row=quad*4+r)
    #pragma unroll
    for (int mask = 1; mask <= 8; mask <<= 1) {
        #pragma unroll
        for (int mt = 0; mt < 2; ++mt)
            #pragma unroll
            for (int r = 0; r < 4; ++r) {
                int b1 = __shfl_xor(m1[mt][r], mask, 64);
                int b2 = __shfl_xor(m2[mt][r], mask, 64);
                int b3 = __shfl_xor(m3[mt][r], mask, 64);
                int lo1 = min(m1[mt][r], b1), hi1 = max(m1[mt][r], b1);
                int lo2 = min(m2[mt][r], b2);
                m1[mt][r] = lo1;
                m2[mt][r] = min(hi1, lo2);
                m3[mt][r] = min(max(hi1, lo2), min(m3[mt][r], b3));
            }
    }

    int jd[2][4];                       // decided winner (or -1) per mt, row quad*4+r
    #pragma unroll
    for (int mt = 0; mt < 2; ++mt)
        #pragma unroll
        for (int r = 0; r < 4; ++r) {
            int k1 = m1[mt][r], k2 = m2[mt][r], k3 = m3[mt][r];
            int g21 = (k2 >> 10) - (k1 >> 10);
            int g31 = (k3 >> 10) - (k1 >> 10);
            int j1 = k1 & 1023;
            float Srow = __shfl(Sloc[mt], quad * 4 + r, 64);   // S of row quad*4+r
            int mq = (int)(Srow * 2.002f) + 5;                 // per-row hard margin
            jd[mt][r] = (g21 > mq) ? j1 : -1;
            if (m16 == 0) {
                int rowG = wrow0 + mt * 16 + quad * 4 + r;
                if (g21 > mq) {
                    out[IDXOFF + rowG] = (float)j1;
                } else if (g31 > mq) {                         // winner in {j1, j2}
                    int p = atomicAdd(&sCnt[0], 1);
                    sPairRow[p] = rowG; sPairJJ[p] = j1 | ((k2 & 1023) << 10);
                } else {                                       // rare: full rescan
                    int p = atomicAdd(&sCnt[1], 1);
                    sFullRow[p] = rowG;
                }
            }
        }

    // decided-row q_st + loss, coalesced: lane = dim; winner broadcast via static shfl
    float part = 0.f;
    #pragma unroll
    for (int i = 0; i < 32; ++i) {      // row i = mt(i>>4)*16 + quad((i&15)>>2)*4 + r(i&3)
        int jr = __shfl(jd[i >> 4][i & 3], ((i & 15) >> 2) * 16, 64);
        if (jr >= 0) {
            #pragma clang fp contract(off)
            int rowG = wrow0 + i;
            float xv = x[rowG * 64 + lane];
            float wv = w[jr * 64 + lane];
            float diff = wv - xv;
            part += diff * diff;
            out[QOFF + rowG * 64 + lane] = xv + diff;
        }
    }
    __syncthreads();                    // LDS lists + counts final
    const int nP = sCnt[0], nF = sCnt[1];

    // Phase P: pairs, thread-per-pair; np-exact compare with first-index tie rule
    for (int p = tid; p < nP; p += 256) {
        int row = sPairRow[p], jj = sPairJJ[p];
        int ja = jj & 1023, jb = (jj >> 10) & 1023;
        if (ja > jb) { int t = ja; ja = jb; jb = t; }
        const float* xr = x + row * 64;
        float cr = np_norm64(xr);
        float da = exact_d(cr, se[ja], exact_dot64(xr, w + ja * 64));
        float db = exact_d(cr, se[jb], exact_dot64(xr, w + jb * 64));
        int win = (db < da) ? jb : ja;
        out[IDXOFF + row] = (float)win;
        const float* e = w + win * 64;
        {
            #pragma clang fp contract(off)
            #pragma unroll
            for (int i2 = 0; i2 < 64; ++i2) {
                float diff = e[i2] - xr[i2];
                part += diff * diff;
                out[QOFF + row * 64 + i2] = xr[i2] + diff;
            }
        }
    }

    // Phase F: full rescans, wave-per-row; wT-coalesced, np-exact (validated order)
    const f32x4* wT4 = (const f32x4*)wT;
    for (int f = wave; f < nF; f += 4) {
        int row = sFullRow[f];
        float xr[64];
        const f32x4* xp = (const f32x4*)(x + row * 64);
        #pragma unroll
        for (int t = 0; t < 16; ++t) {
            f32x4 v = xp[t];
            xr[4 * t] = v[0]; xr[4 * t + 1] = v[1]; xr[4 * t + 2] = v[2]; xr[4 * t + 3] = v[3];
        }
        float cr = np_norm64(xr);
        float bd = 3.402823466e38f; int bj = 0;
        #pragma unroll
        for (int g = 0; g < 4; ++g) {                    // pass g: codes g*256 + 4*lane + c
            f32x4 a0 = {0.f,0.f,0.f,0.f}, a1 = a0, a2 = a0, a3 = a0;
            #pragma unroll 4
            for (int i2 = 0; i2 < 64; i2 += 4) {
                f32x4 w0 = wT4[(i2 + 0) * 256 + g * 64 + lane];
                f32x4 w1 = wT4[(i2 + 1) * 256 + g * 64 + lane];
                f32x4 w2 = wT4[(i2 + 2) * 256 + g * 64 + lane];
                f32x4 w3 = wT4[(i2 + 3) * 256 + g * 64 + lane];
                #pragma unroll
                for (int c = 0; c < 4; ++c) {
                    a0[c] = fmaf(xr[i2 + 0], w0[c], a0[c]);
                    a1[c] = fmaf(xr[i2 + 1], w1[c], a1[c]);
                    a2[c] = fmaf(xr[i2 + 2], w2[c], a2[c]);
                    a3[c] = fmaf(xr[i2 + 3], w3[c], a3[c]);
                }
            }
            #pragma unroll
            for (int c = 0; c < 4; ++c) {
                float dot = (a0[c] + a1[c]) + (a2[c] + a3[c]);
                int j = g * 256 + lane * 4 + c;
                float d = exact_d(cr, se[j], dot);
                if (d < bd) { bd = d; bj = j; }          // per-lane j ascending => np tie rule
            }
        }
        for (int mask = 1; mask < 64; mask <<= 1) {
            float od = __shfl_xor(bd, mask, 64);
            int   oj = __shfl_xor(bj, mask, 64);
            if (od < bd || (od == bd && oj < bj)) { bd = od; bj = oj; }
        }
        {
            #pragma clang fp contract(off)
            float xv = x[row * 64 + lane];
            float wv = w[bj * 64 + lane];
            float diff = wv - xv;
            part += diff * diff;
            out[QOFF + row * 64 + lane] = xv + diff;
        }
        if (lane == 0) out[IDXOFF + row] = (float)bj;
    }

    // block loss partial
    for (int off = 32; off > 0; off >>= 1) part += __shfl_down(part, off, 64);
    if (lane == 0) sPart[wave] = part;
    __syncthreads();
    if (tid == 0) partial[blockIdx.x] = (sPart[0] + sPart[1]) + (sPart[2] + sPart[3]);
}

// ---------- loss: single block sums the 1024 per-block partials, one writer ----------
__global__ __launch_bounds__(256) void vq_loss(const float* __restrict__ partial,
                                               float* __restrict__ out) {
    __shared__ float red[4];
    const int tid = threadIdx.x, lane = tid & 63, wave = tid >> 6;
    float s = 0.f;
    #pragma unroll
    for (int t = 0; t < 4; ++t) s += partial[t * 256 + tid];   // 4*256 = 1024 = NSCR
    for (int off = 32; off > 0; off >>= 1) s += __shfl_down(s, off, 64);
    if (lane == 0) red[wave] = s;
    __syncthreads();
    if (tid == 0) out[0] = ((red[0] + red[1]) + (red[2] + red[3])) * (1.25f / 8388608.0f);
}

extern "C" void kernel_launch(void* const* d_in, const int* in_sizes, int n_in,
                              void* d_out, int out_size, void* d_ws, size_t ws_size,
                              hipStream_t stream) {
    const float* x = (const float*)d_in[0];
    const float* w = (const float*)d_in[1];
    float* out = (float*)d_out;

    unsigned short* Gf = (unsigned short*)d_ws;                  // 128 KB fragment-order fp16
    float* se   = (float*)((char*)d_ws + 131072);                // 4 KB
    float* se20 = (float*)((char*)d_ws + 135168);                // 4 KB
    float* wT   = (float*)((char*)d_ws + 139264);                // 256 KB column-major fp32
    float* partial = (float*)((char*)d_ws + 401408);             // 4 KB (1024 floats)

    vq_prep<<<32, 256, 0, stream>>>(w, Gf, wT, se, se20);
    vq_screen<<<NSCR, 256, 0, stream>>>(x, w, Gf, se20, se, wT, out, partial);
    vq_loss<<<1, 256, 0, stream>>>(partial, out);
}

// Round 11
// 181.607 us; speedup vs baseline: 1.1001x; 1.1001x over previous
//
#include <hip/hip_runtime.h>

#define NROWS   131072
#define DIM     64
#define K       1024
#define QOFF    1
#define IDXOFF  8388609        // 1 + NROWS*DIM
// Per-row routing margin in 2^-20 distance units: hard error of the fp16 screen
// is 2^-19 * sum|x_i| per distance => 2*S units.  mq = 2.002*S + 5 covers
// fp32 S-summation slack, MFMA fp32 accumulation (<=1), trunc quant (2), ceil (1).
#define NSCR    1024           // screen grid (128 rows/block, 4 blocks/CU)
#define NFIN    1024           // finish grid

typedef float    f32x4 __attribute__((ext_vector_type(4)));
typedef _Float16 f16x8 __attribute__((ext_vector_type(8)));

// ---------- np-exact arithmetic (validated: absmax 0.0) ----------
__device__ __forceinline__ float np_norm64(const float* v) {
    #pragma clang fp contract(off)
    float r[8];
    #pragma unroll
    for (int k = 0; k < 8; ++k) r[k] = v[k] * v[k];
    #pragma unroll
    for (int i = 8; i < 64; i += 8)
        #pragma unroll
        for (int k = 0; k < 8; ++k) r[k] += v[i + k] * v[i + k];
    return ((r[0] + r[1]) + (r[2] + r[3])) + ((r[4] + r[5]) + (r[6] + r[7]));
}
__device__ __forceinline__ float exact_dot64(const float* __restrict__ xr,
                                             const float* __restrict__ e) {
    float a0 = 0.f, a1 = 0.f, a2 = 0.f, a3 = 0.f;
    #pragma unroll
    for (int i = 0; i < 64; i += 4) {
        a0 = fmaf(xr[i + 0], e[i + 0], a0);
        a1 = fmaf(xr[i + 1], e[i + 1], a1);
        a2 = fmaf(xr[i + 2], e[i + 2], a2);
        a3 = fmaf(xr[i + 3], e[i + 3], a3);
    }
    return (a0 + a1) + (a2 + a3);
}
__device__ __forceinline__ float exact_d(float cr, float sej, float dot) {
    #pragma clang fp contract(off)
    float t = cr + sej;
    return t - 2.0f * dot;
}

// ---------- prep v2: 256 blocks.  Transpose 1 elem/thread; Gf on blocks 0..31;
// se on blocks 32..63 via 8-lane stripe+xor-tree (bit-identical to np_norm64) ----------
__global__ __launch_bounds__(256) void vq_prep(
    const float* __restrict__ w, unsigned short* __restrict__ Gf,
    float* __restrict__ wT, float* __restrict__ se, float* __restrict__ se20,
    int* __restrict__ gcnt) {
    const int b = blockIdx.x, t = threadIdx.x;
    const int g = b * 256 + t;                       // 0..65535
    if (g < 2) gcnt[g] = 0;
    // transpose: wT[i*1024 + j] = w[j*64 + i]  (coalesced write, 1 elem/thread)
    wT[g] = w[(g & 1023) * 64 + (g >> 10)];
    if (b < 32) {
        // Gf fragment-order fp16: gid = ntile*128 + c*64 + lane
        int gid = g;
        int lane = gid & 63, c = (gid >> 6) & 1, ntile = gid >> 7;
        int code = ntile * 16 + (lane & 15);
        int k0 = c * 32 + (lane >> 4) * 8;
        const float* rowp = w + code * 64 + k0;
        f16x8 h8;
        #pragma unroll
        for (int j = 0; j < 8; ++j) h8[j] = (_Float16)(rowp[j] * 1024.0f);  // *1024 exact
        *(f16x8*)(Gf + gid * 8) = h8;
    } else if (b < 64) {
        // se: 8 codes per wave, 8 lanes per code; stripe st accumulates r[st] then
        // xor-tree 1/2/4 reproduces ((r0+r1)+(r2+r3))+((r4+r5)+(r6+r7)) exactly.
        #pragma clang fp contract(off)
        int wv = (b - 32) * 4 + (t >> 6);            // 0..127
        int k = t & 63;
        int code = wv * 8 + (k >> 3), st = k & 7;
        const float* e = w + code * 64 + st;
        float r = 0.f;
        #pragma unroll
        for (int i = 0; i < 8; ++i) { float v = e[8 * i]; r += v * v; }  // 0+v0*v0 exact
        r += __shfl_xor(r, 1, 64);
        r += __shfl_xor(r, 2, 64);
        r += __shfl_xor(r, 4, 64);
        if (st == 0) { se[code] = r; se20[code] = r * 1048576.0f; }
    }
}

// ---------- screen: fp16 MFMA scan, 2 m-tiles/wave, packed-int top-3 (R8, 74us) --------
__global__ __launch_bounds__(256, 4) void vq_screen(
    const float* __restrict__ x, const float* __restrict__ w,
    const unsigned short* __restrict__ Gf, const float* __restrict__ se20,
    float* __restrict__ out, float* __restrict__ partial, int* __restrict__ gcnt,
    int* __restrict__ pairRows, int* __restrict__ pairJJ, int* __restrict__ fullRows) {
    __shared__ float sSe[1024];         // 4 KB: se*2^20
    __shared__ float sPart[4];
    __shared__ int sCnt[2], sBase[2];
    __shared__ int sPairRow[128], sPairJJ[128], sFullRow[128];
    const int tid  = threadIdx.x;
    const int wave = tid >> 6, lane = tid & 63;
    const int quad = lane >> 4, m16 = lane & 15;
    const int wrow0 = blockIdx.x * 128 + wave * 32;

    if (tid < 2) sCnt[tid] = 0;
    #pragma unroll
    for (int t = 0; t < 4; ++t) sSe[t * 256 + tid] = se20[t * 256 + tid];

    // A fragments: fp16(x), A[m = m16][k = quad*8 + j], chunk c: k = 32c..32c+31
    f16x8 Ah[2][2];
    float Sloc[2] = {0.f, 0.f};
    #pragma unroll
    for (int mt = 0; mt < 2; ++mt)
        #pragma unroll
        for (int c = 0; c < 2; ++c) {
            const float* p = x + (wrow0 + mt * 16 + m16) * 64 + c * 32 + quad * 8;
            f32x4 u0 = *(const f32x4*)p;
            f32x4 u1 = *(const f32x4*)(p + 4);
            #pragma unroll
            for (int j = 0; j < 8; ++j) {
                float xv = (j < 4) ? u0[j] : u1[j - 4];
                Ah[mt][c][j] = (_Float16)xv;
                Sloc[mt] += fabsf(xv);
            }
        }
    #pragma unroll
    for (int mt = 0; mt < 2; ++mt) {
        Sloc[mt] += __shfl_xor(Sloc[mt], 16, 64);
        Sloc[mt] += __shfl_xor(Sloc[mt], 32, 64);   // every lane: S(row = its m16)
    }

    int m1[2][4], m2[2][4], m3[2][4];
    #pragma unroll
    for (int mt = 0; mt < 2; ++mt)
        #pragma unroll
        for (int r = 0; r < 4; ++r) {
            m1[mt][r] = 0x7fffffff; m2[mt][r] = 0x7fffffff; m3[mt][r] = 0x7fffffff;
        }

    __syncthreads();                    // sSe + sCnt ready

    #pragma unroll 8
    for (int t = 0; t < 64; ++t) {      // 64 code-tiles of 16
        f16x8 B0 = *(const f16x8*)(Gf + t * 1024 + lane * 8);        // chunk 0, coalesced
        f16x8 B1 = *(const f16x8*)(Gf + t * 1024 + 512 + lane * 8);  // chunk 1
        float sen = sSe[t * 16 + m16];
        int jn = t * 16 + m16;
        #pragma unroll
        for (int mt = 0; mt < 2; ++mt) {
            f32x4 acc = {0.f, 0.f, 0.f, 0.f};
            acc = __builtin_amdgcn_mfma_f32_16x16x32_f16(Ah[mt][0], B0, acc, 0, 0, 0);
            acc = __builtin_amdgcn_mfma_f32_16x16x32_f16(Ah[mt][1], B1, acc, 0, 0, 0);
            #pragma unroll
            for (int r = 0; r < 4; ++r) {
                // f*2^20 = se*2^20 - 2*2^-10*2^20*dot' ; dot' = 1024*x.e
                float kf = fmaf(acc[r], -2048.0f, sen);
                int q = (int)kf;                              // trunc: monotone
                int key = (int)((unsigned)q << 10) | jn;
                int a  = max(m2[mt][r], key);                 // old m2
                int t2 = max(m1[mt][r], key);                 // old m1
                m3[mt][r] = min(m3[mt][r], a);
                m2[mt][r] = min(m2[mt][r], t2);
                m1[mt][r] = min(m1[mt][r], key);
            }
        }
    }

    // butterfly all-reduce top-3 over the 16 cols (C layout: col=m16, row=quad*4+r)
    #pragma unroll
    for (int mask = 1; mask <= 8; mask <<= 1) {
        #pragma unroll
        for (int mt = 0; mt < 2; ++mt)
            #pragma unroll
            for (int r = 0; r < 4; ++r) {
                int b1 = __shfl_xor(m1[mt][r], mask, 64);
                int b2 = __shfl_xor(m2[mt][r], mask, 64);
                int b3 = __shfl_xor(m3[mt][r], mask, 64);
                int lo1 = min(m1[mt][r], b1), hi1 = max(m1[mt][r], b1);
                int lo2 = min(m2[mt][r], b2);
                m1[mt][r] = lo1;
                m2[mt][r] = min(hi1, lo2);
                m3[mt][r] = min(max(hi1, lo2), min(m3[mt][r], b3));
            }
    }

    int jd[2][4];                       // decided winner (or -1) per mt, row quad*4+r
    #pragma unroll
    for (int mt = 0; mt < 2; ++mt)
        #pragma unroll
        for (int r = 0; r < 4; ++r) {
            int k1 = m1[mt][r], k2 = m2[mt][r], k3 = m3[mt][r];
            int g21 = (k2 >> 10) - (k1 >> 10);
            int g31 = (k3 >> 10) - (k1 >> 10);
            int j1 = k1 & 1023;
            float Srow = __shfl(Sloc[mt], quad * 4 + r, 64);   // S of row quad*4+r
            int mq = (int)(Srow * 2.002f) + 5;                 // per-row hard margin
            jd[mt][r] = (g21 > mq) ? j1 : -1;
            if (m16 == 0) {
                int rowG = wrow0 + mt * 16 + quad * 4 + r;
                if (g21 > mq) {
                    out[IDXOFF + rowG] = (float)j1;
                } else if (g31 > mq) {                         // winner in {j1, j2}
                    int p = atomicAdd(&sCnt[0], 1);
                    sPairRow[p] = rowG; sPairJJ[p] = j1 | ((k2 & 1023) << 10);
                } else {                                       // rare: full rescan
                    int p = atomicAdd(&sCnt[1], 1);
                    sFullRow[p] = rowG;
                }
            }
        }

    // q_st + loss for decided rows, coalesced: lane = dim; winner broadcast via static shfl
    float part = 0.f;
    #pragma unroll
    for (int i = 0; i < 32; ++i) {      // row i = mt(i>>4)*16 + quad((i&15)>>2)*4 + r(i&3)
        int jr = __shfl(jd[i >> 4][i & 3], ((i & 15) >> 2) * 16, 64);
        if (jr >= 0) {
            #pragma clang fp contract(off)
            int rowG = wrow0 + i;
            float xv = x[rowG * 64 + lane];
            float wv = w[jr * 64 + lane];
            float diff = wv - xv;
            part += diff * diff;
            out[QOFF + rowG * 64 + lane] = xv + diff;
        }
    }
    for (int off = 32; off > 0; off >>= 1) part += __shfl_down(part, off, 64);
    if (lane == 0) sPart[wave] = part;
    __syncthreads();                    // sPart + LDS lists + sCnt final
    if (tid == 0) {
        partial[blockIdx.x] = (sPart[0] + sPart[1]) + (sPart[2] + sPart[3]);
        int np_ = sCnt[0], nf = sCnt[1];
        sBase[0] = np_ ? atomicAdd(&gcnt[0], np_) : 0;     // one atomic per block/category
        sBase[1] = nf  ? atomicAdd(&gcnt[1], nf)  : 0;
    }
    __syncthreads();                    // sBase ready
    if (tid < sCnt[0]) {
        int d = sBase[0] + tid;
        pairRows[d] = sPairRow[tid]; pairJJ[d] = sPairJJ[tid];
    }
    if (tid < sCnt[1]) fullRows[sBase[1] + tid] = sFullRow[tid];
}

// ---------- finish: dense lists; exact pair-compares (thread) + coalesced full rescans ----
__global__ __launch_bounds__(256) void vq_finish(
    const float* __restrict__ x, const float* __restrict__ w, const float* __restrict__ wT,
    const float* __restrict__ se, float* __restrict__ out, float* __restrict__ partial,
    const int* __restrict__ gcnt, const int* __restrict__ pairRows,
    const int* __restrict__ pairJJ, const int* __restrict__ fullRows) {
    __shared__ float sPart[4];
    const int tid = threadIdx.x;
    const int lane = tid & 63, wave = tid >> 6;
    const int nPair = gcnt[0], nFull = gcnt[1];
    const int gthread = blockIdx.x * 256 + tid, nThreads = gridDim.x * 256;
    const int gwave = blockIdx.x * 4 + wave,   nWaves = gridDim.x * 4;
    float part = 0.f;

    // Phase A: winner in {ja, jb}; exact compare with np first-index tie rule
    for (int i = gthread; i < nPair; i += nThreads) {
        int row = pairRows[i], jj = pairJJ[i];
        int ja = jj & 1023, jb = (jj >> 10) & 1023;
        if (ja > jb) { int t = ja; ja = jb; jb = t; }
        float xr[64];
        const f32x4* xp = (const f32x4*)(x + row * 64);
        #pragma unroll
        for (int t = 0; t < 16; ++t) {
            f32x4 v = xp[t];
            xr[4 * t] = v[0]; xr[4 * t + 1] = v[1]; xr[4 * t + 2] = v[2]; xr[4 * t + 3] = v[3];
        }
        float cr = np_norm64(xr);
        float da = exact_d(cr, se[ja], exact_dot64(xr, w + ja * 64));
        float db = exact_d(cr, se[jb], exact_dot64(xr, w + jb * 64));
        int win = (db < da) ? jb : ja;
        out[IDXOFF + row] = (float)win;
        const float* e = w + win * 64;
        {
            #pragma clang fp contract(off)
            #pragma unroll
            for (int i2 = 0; i2 < 64; ++i2) {
                float diff = e[i2] - xr[i2];
                part += diff * diff;
                out[QOFF + row * 64 + i2] = xr[i2] + diff;
            }
        }
    }

    // Phase B: full exact rescan, one row per wave.  Coalesced via wT; the 4-stripe
    // accumulator order (q = i&3, dims ascending) is bit-identical to exact_dot64.
    const f32x4* wT4 = (const f32x4*)wT;
    for (int i = gwave; i < nFull; i += nWaves) {
        int row = fullRows[i];
        float xr[64];                                    // same row for all lanes (broadcast)
        const f32x4* xp = (const f32x4*)(x + row * 64);
        #pragma unroll
        for (int t = 0; t < 16; ++t) {
            f32x4 v = xp[t];
            xr[4 * t] = v[0]; xr[4 * t + 1] = v[1]; xr[4 * t + 2] = v[2]; xr[4 * t + 3] = v[3];
        }
        float cr = np_norm64(xr);
        float bd = 3.402823466e38f; int bj = 0;
        #pragma unroll
        for (int g = 0; g < 4; ++g) {                    // pass g: codes g*256 + 4*lane + c
            f32x4 a0 = {0.f,0.f,0.f,0.f}, a1 = a0, a2 = a0, a3 = a0;
            #pragma unroll 4
            for (int i2 = 0; i2 < 64; i2 += 4) {
                f32x4 w0 = wT4[(i2 + 0) * 256 + g * 64 + lane];
                f32x4 w1 = wT4[(i2 + 1) * 256 + g * 64 + lane];
                f32x4 w2 = wT4[(i2 + 2) * 256 + g * 64 + lane];
                f32x4 w3 = wT4[(i2 + 3) * 256 + g * 64 + lane];
                #pragma unroll
                for (int c = 0; c < 4; ++c) {
                    a0[c] = fmaf(xr[i2 + 0], w0[c], a0[c]);
                    a1[c] = fmaf(xr[i2 + 1], w1[c], a1[c]);
                    a2[c] = fmaf(xr[i2 + 2], w2[c], a2[c]);
                    a3[c] = fmaf(xr[i2 + 3], w3[c], a3[c]);
                }
            }
            #pragma unroll
            for (int c = 0; c < 4; ++c) {
                float dot = (a0[c] + a1[c]) + (a2[c] + a3[c]);
                int j = g * 256 + lane * 4 + c;
                float d = exact_d(cr, se[j], dot);
                if (d < bd) { bd = d; bj = j; }          // per-lane j ascending => np tie rule
            }
        }
        for (int mask = 1; mask < 64; mask <<= 1) {
            float od = __shfl_xor(bd, mask, 64);
            int   oj = __shfl_xor(bj, mask, 64);
            if (od < bd || (od == bd && oj < bj)) { bd = od; bj = oj; }
        }
        {
            #pragma clang fp contract(off)
            float xv = x[row * 64 + lane];
            float wv = w[bj * 64 + lane];
            float diff = wv - xv;
            part += diff * diff;
            out[QOFF + row * 64 + lane] = xv + diff;
        }
        if (lane == 0) out[IDXOFF + row] = (float)bj;
    }

    for (int off = 32; off > 0; off >>= 1) part += __shfl_down(part, off, 64);
    if (lane == 0) sPart[wave] = part;
    __syncthreads();
    if (tid == 0) partial[NSCR + blockIdx.x] = (sPart[0] + sPart[1]) + (sPart[2] + sPart[3]);
}

// ---------- loss: single block sums the 2048 per-block partials, one writer ----------
__global__ __launch_bounds__(256) void vq_loss(const float* __restrict__ partial,
                                               float* __restrict__ out) {
    __shared__ float red[4];
    const int tid = threadIdx.x, lane = tid & 63, wave = tid >> 6;
    float s = 0.f;
    #pragma unroll
    for (int t = 0; t < 8; ++t) s += partial[t * 256 + tid];   // 8*256 = 2048 = NSCR+NFIN
    for (int off = 32; off > 0; off >>= 1) s += __shfl_down(s, off, 64);
    if (lane == 0) red[wave] = s;
    __syncthreads();
    if (tid == 0) out[0] = ((red[0] + red[1]) + (red[2] + red[3])) * (1.25f / 8388608.0f);
}

extern "C" void kernel_launch(void* const* d_in, const int* in_sizes, int n_in,
                              void* d_out, int out_size, void* d_ws, size_t ws_size,
                              hipStream_t stream) {
    const float* x = (const float*)d_in[0];
    const float* w = (const float*)d_in[1];
    float* out = (float*)d_out;

    unsigned short* Gf = (unsigned short*)d_ws;                  // 128 KB fragment-order fp16
    float* se   = (float*)((char*)d_ws + 131072);                // 4 KB
    float* se20 = (float*)((char*)d_ws + 135168);                // 4 KB
    float* wT   = (float*)((char*)d_ws + 139264);                // 256 KB column-major fp32
    int* gcnt   = (int*)((char*)d_ws + 401408);                  // 8 B (pad to 512)
    int* pairRows = (int*)((char*)d_ws + 401920);                // 512 KB worst case
    int* pairJJ   = pairRows + NROWS;                            // 512 KB
    int* fullRows = pairJJ + NROWS;                              // 512 KB
    float* partial = (float*)(fullRows + NROWS);                 // 8 KB (2048 floats)

    vq_prep<<<256, 256, 0, stream>>>(w, Gf, wT, se, se20, gcnt);
    vq_screen<<<NSCR, 256, 0, stream>>>(x, w, Gf, se20, out, partial, gcnt,
                                        pairRows, pairJJ, fullRows);
    vq_finish<<<NFIN, 256, 0, stream>>>(x, w, wT, se, out, partial, gcnt,
                                        pairRows, pairJJ, fullRows);
    vq_loss<<<1, 256, 0, stream>>>(partial, out);
}

// Round 12
// 174.429 us; speedup vs baseline: 1.1454x; 1.0412x over previous
//
#include <hip/hip_runtime.h>

#define NROWS   131072
#define DIM     64
#define K       1024
#define QOFF    1
#define IDXOFF  8388609        // 1 + NROWS*DIM
// Per-row routing margin in 2^-20 distance units: hard error of the fp16 screen
// is 2^-19 * sum|x_i| per distance => 2*S units.  mq = 2.002*S + 5 covers
// fp32 S-summation slack, MFMA fp32 accumulation (<=1), trunc quant (2), ceil (1).
#define NSCR    1024           // screen grid (128 rows/block, 4 blocks/CU)
#define NFIN    1024           // finish grid

typedef float    f32x4 __attribute__((ext_vector_type(4)));
typedef _Float16 f16x8 __attribute__((ext_vector_type(8)));

// ---------- np-exact arithmetic (validated: absmax 0.0) ----------
__device__ __forceinline__ float np_norm64(const float* v) {
    #pragma clang fp contract(off)
    float r[8];
    #pragma unroll
    for (int k = 0; k < 8; ++k) r[k] = v[k] * v[k];
    #pragma unroll
    for (int i = 8; i < 64; i += 8)
        #pragma unroll
        for (int k = 0; k < 8; ++k) r[k] += v[i + k] * v[i + k];
    return ((r[0] + r[1]) + (r[2] + r[3])) + ((r[4] + r[5]) + (r[6] + r[7]));
}
__device__ __forceinline__ float exact_dot64(const float* __restrict__ xr,
                                             const float* __restrict__ e) {
    float a0 = 0.f, a1 = 0.f, a2 = 0.f, a3 = 0.f;
    #pragma unroll
    for (int i = 0; i < 64; i += 4) {
        a0 = fmaf(xr[i + 0], e[i + 0], a0);
        a1 = fmaf(xr[i + 1], e[i + 1], a1);
        a2 = fmaf(xr[i + 2], e[i + 2], a2);
        a3 = fmaf(xr[i + 3], e[i + 3], a3);
    }
    return (a0 + a1) + (a2 + a3);
}
__device__ __forceinline__ float exact_d(float cr, float sej, float dot) {
    #pragma clang fp contract(off)
    float t = cr + sej;
    return t - 2.0f * dot;
}

// ---------- prep v2: 256 blocks.  Transpose 1 elem/thread; Gf on blocks 0..31;
// se on blocks 32..63 via 8-lane stripe+xor-tree (bit-identical to np_norm64) ----------
__global__ __launch_bounds__(256) void vq_prep(
    const float* __restrict__ w, unsigned short* __restrict__ Gf,
    float* __restrict__ wT, float* __restrict__ se, float* __restrict__ se20,
    int* __restrict__ gcnt) {
    const int b = blockIdx.x, t = threadIdx.x;
    const int g = b * 256 + t;                       // 0..65535
    if (g < 2) gcnt[g] = 0;
    // transpose: wT[i*1024 + j] = w[j*64 + i]  (coalesced write, 1 elem/thread)
    wT[g] = w[(g & 1023) * 64 + (g >> 10)];
    if (b < 32) {
        // Gf fragment-order fp16: gid = ntile*128 + c*64 + lane
        int gid = g;
        int lane = gid & 63, c = (gid >> 6) & 1, ntile = gid >> 7;
        int code = ntile * 16 + (lane & 15);
        int k0 = c * 32 + (lane >> 4) * 8;
        const float* rowp = w + code * 64 + k0;
        f16x8 h8;
        #pragma unroll
        for (int j = 0; j < 8; ++j) h8[j] = (_Float16)(rowp[j] * 1024.0f);  // *1024 exact
        *(f16x8*)(Gf + gid * 8) = h8;
    } else if (b < 64) {
        // se: 8 codes per wave, 8 lanes per code; stripe st accumulates r[st] then
        // xor-tree 1/2/4 reproduces ((r0+r1)+(r2+r3))+((r4+r5)+(r6+r7)) exactly.
        #pragma clang fp contract(off)
        int wv = (b - 32) * 4 + (t >> 6);            // 0..127
        int k = t & 63;
        int code = wv * 8 + (k >> 3), st = k & 7;
        const float* e = w + code * 64 + st;
        float r = 0.f;
        #pragma unroll
        for (int i = 0; i < 8; ++i) { float v = e[8 * i]; r += v * v; }  // 0+v0*v0 exact
        r += __shfl_xor(r, 1, 64);
        r += __shfl_xor(r, 2, 64);
        r += __shfl_xor(r, 4, 64);
        if (st == 0) { se[code] = r; se20[code] = r * 1048576.0f; }
    }
}

// ---------- screen: fp16 MFMA scan, 2 m-tiles/wave, DEPTH-4 REG PREFETCH on B ----------
// block = 256 (4 waves); TWO 16-row m-tiles per wave (32 rows); grid = 1024 (4 blocks/CU).
// B loads circulate through a 4-slot register buffer: issue->use gap = 4 iterations
// (~480 cy) > L2 latency, so the per-tile vmcnt stall disappears.  Slot index t&3 is
// compile-time inside the unroll-8 body (tt % 8 == 0 => t&3 == k&3).
__global__ __launch_bounds__(256, 4) void vq_screen(
    const float* __restrict__ x, const float* __restrict__ w,
    const unsigned short* __restrict__ Gf, const float* __restrict__ se20,
    float* __restrict__ out, float* __restrict__ partial, int* __restrict__ gcnt,
    int* __restrict__ pairRows, int* __restrict__ pairJJ, int* __restrict__ fullRows) {
    __shared__ float sSe[1024];         // 4 KB: se*2^20
    __shared__ float sPart[4];
    __shared__ int sCnt[2], sBase[2];
    __shared__ int sPairRow[128], sPairJJ[128], sFullRow[128];
    const int tid  = threadIdx.x;
    const int wave = tid >> 6, lane = tid & 63;
    const int quad = lane >> 4, m16 = lane & 15;
    const int wrow0 = blockIdx.x * 128 + wave * 32;

    if (tid < 2) sCnt[tid] = 0;
    #pragma unroll
    for (int t = 0; t < 4; ++t) sSe[t * 256 + tid] = se20[t * 256 + tid];

    // A fragments: fp16(x), A[m = m16][k = quad*8 + j], chunk c: k = 32c..32c+31
    f16x8 Ah[2][2];
    float Sloc[2] = {0.f, 0.f};
    #pragma unroll
    for (int mt = 0; mt < 2; ++mt)
        #pragma unroll
        for (int c = 0; c < 2; ++c) {
            const float* p = x + (wrow0 + mt * 16 + m16) * 64 + c * 32 + quad * 8;
            f32x4 u0 = *(const f32x4*)p;
            f32x4 u1 = *(const f32x4*)(p + 4);
            #pragma unroll
            for (int j = 0; j < 8; ++j) {
                float xv = (j < 4) ? u0[j] : u1[j - 4];
                Ah[mt][c][j] = (_Float16)xv;
                Sloc[mt] += fabsf(xv);
            }
        }
    #pragma unroll
    for (int mt = 0; mt < 2; ++mt) {
        Sloc[mt] += __shfl_xor(Sloc[mt], 16, 64);
        Sloc[mt] += __shfl_xor(Sloc[mt], 32, 64);   // every lane: S(row = its m16)
    }

    int m1[2][4], m2[2][4], m3[2][4];
    #pragma unroll
    for (int mt = 0; mt < 2; ++mt)
        #pragma unroll
        for (int r = 0; r < 4; ++r) {
            m1[mt][r] = 0x7fffffff; m2[mt][r] = 0x7fffffff; m3[mt][r] = 0x7fffffff;
        }

    // prime the 4-slot B prefetch ring (tiles 0..3)
    f16x8 pb0[4], pb1[4];
    #pragma unroll
    for (int i = 0; i < 4; ++i) {
        pb0[i] = *(const f16x8*)(Gf + i * 1024 + lane * 8);
        pb1[i] = *(const f16x8*)(Gf + i * 1024 + 512 + lane * 8);
    }

    __syncthreads();                    // sSe + sCnt ready

    for (int tt = 0; tt < 64; tt += 8) {
        #pragma unroll
        for (int k = 0; k < 8; ++k) {
            const int t = tt + k;
            const int s = k & 3;                         // == t & 3 (tt % 8 == 0)
            f16x8 B0 = pb0[s], B1 = pb1[s];
            int tn = t + 4; tn = (tn > 63) ? 63 : tn;    // clamped (redundant tail loads ok)
            pb0[s] = *(const f16x8*)(Gf + tn * 1024 + lane * 8);
            pb1[s] = *(const f16x8*)(Gf + tn * 1024 + 512 + lane * 8);
            float sen = sSe[t * 16 + m16];
            int jn = t * 16 + m16;
            #pragma unroll
            for (int mt = 0; mt < 2; ++mt) {
                f32x4 acc = {0.f, 0.f, 0.f, 0.f};
                acc = __builtin_amdgcn_mfma_f32_16x16x32_f16(Ah[mt][0], B0, acc, 0, 0, 0);
                acc = __builtin_amdgcn_mfma_f32_16x16x32_f16(Ah[mt][1], B1, acc, 0, 0, 0);
                #pragma unroll
                for (int r = 0; r < 4; ++r) {
                    // f*2^20 = se*2^20 - 2*2^-10*2^20*dot' ; dot' = 1024*x.e
                    float kf = fmaf(acc[r], -2048.0f, sen);
                    int q = (int)kf;                              // trunc: monotone
                    int key = (int)((unsigned)q << 10) | jn;
                    int a  = max(m2[mt][r], key);                 // old m2
                    int t2 = max(m1[mt][r], key);                 // old m1
                    m3[mt][r] = min(m3[mt][r], a);
                    m2[mt][r] = min(m2[mt][r], t2);
                    m1[mt][r] = min(m1[mt][r], key);
                }
            }
        }
    }

    // butterfly all-reduce top-3 over the 16 cols (C layout: col=m16, row=quad*4+r)
    #pragma unroll
    for (int mask = 1; mask <= 8; mask <<= 1) {
        #pragma unroll
        for (int mt = 0; mt < 2; ++mt)
            #pragma unroll
            for (int r = 0; r < 4; ++r) {
                int b1 = __shfl_xor(m1[mt][r], mask, 64);
                int b2 = __shfl_xor(m2[mt][r], mask, 64);
                int b3 = __shfl_xor(m3[mt][r], mask, 64);
                int lo1 = min(m1[mt][r], b1), hi1 = max(m1[mt][r], b1);
                int lo2 = min(m2[mt][r], b2);
                m1[mt][r] = lo1;
                m2[mt][r] = min(hi1, lo2);
                m3[mt][r] = min(max(hi1, lo2), min(m3[mt][r], b3));
            }
    }

    int jd[2][4];                       // decided winner (or -1) per mt, row quad*4+r
    #pragma unroll
    for (int mt = 0; mt < 2; ++mt)
        #pragma unroll
        for (int r = 0; r < 4; ++r) {
            int k1 = m1[mt][r], k2 = m2[mt][r], k3 = m3[mt][r];
            int g21 = (k2 >> 10) - (k1 >> 10);
            int g31 = (k3 >> 10) - (k1 >> 10);
            int j1 = k1 & 1023;
            float Srow = __shfl(Sloc[mt], quad * 4 + r, 64);   // S of row quad*4+r
            int mq = (int)(Srow * 2.002f) + 5;                 // per-row hard margin
            jd[mt][r] = (g21 > mq) ? j1 : -1;
            if (m16 == 0) {
                int rowG = wrow0 + mt * 16 + quad * 4 + r;
                if (g21 > mq) {
                    out[IDXOFF + rowG] = (float)j1;
                } else if (g31 > mq) {                         // winner in {j1, j2}
                    int p = atomicAdd(&sCnt[0], 1);
                    sPairRow[p] = rowG; sPairJJ[p] = j1 | ((k2 & 1023) << 10);
                } else {                                       // rare: full rescan
                    int p = atomicAdd(&sCnt[1], 1);
                    sFullRow[p] = rowG;
                }
            }
        }

    // q_st + loss for decided rows, coalesced: lane = dim; winner broadcast via static shfl
    float part = 0.f;
    #pragma unroll
    for (int i = 0; i < 32; ++i) {      // row i = mt(i>>4)*16 + quad((i&15)>>2)*4 + r(i&3)
        int jr = __shfl(jd[i >> 4][i & 3], ((i & 15) >> 2) * 16, 64);
        if (jr >= 0) {
            #pragma clang fp contract(off)
            int rowG = wrow0 + i;
            float xv = x[rowG * 64 + lane];
            float wv = w[jr * 64 + lane];
            float diff = wv - xv;
            part += diff * diff;
            out[QOFF + rowG * 64 + lane] = xv + diff;
        }
    }
    for (int off = 32; off > 0; off >>= 1) part += __shfl_down(part, off, 64);
    if (lane == 0) sPart[wave] = part;
    __syncthreads();                    // sPart + LDS lists + sCnt final
    if (tid == 0) {
        partial[blockIdx.x] = (sPart[0] + sPart[1]) + (sPart[2] + sPart[3]);
        int np_ = sCnt[0], nf = sCnt[1];
        sBase[0] = np_ ? atomicAdd(&gcnt[0], np_) : 0;     // one atomic per block/category
        sBase[1] = nf  ? atomicAdd(&gcnt[1], nf)  : 0;
    }
    __syncthreads();                    // sBase ready
    if (tid < sCnt[0]) {
        int d = sBase[0] + tid;
        pairRows[d] = sPairRow[tid]; pairJJ[d] = sPairJJ[tid];
    }
    if (tid < sCnt[1]) fullRows[sBase[1] + tid] = sFullRow[tid];
}

// ---------- finish: dense lists; exact pair-compares (thread) + coalesced full rescans ----
__global__ __launch_bounds__(256) void vq_finish(
    const float* __restrict__ x, const float* __restrict__ w, const float* __restrict__ wT,
    const float* __restrict__ se, float* __restrict__ out, float* __restrict__ partial,
    const int* __restrict__ gcnt, const int* __restrict__ pairRows,
    const int* __restrict__ pairJJ, const int* __restrict__ fullRows) {
    __shared__ float sPart[4];
    const int tid = threadIdx.x;
    const int lane = tid & 63, wave = tid >> 6;
    const int nPair = gcnt[0], nFull = gcnt[1];
    const int gthread = blockIdx.x * 256 + tid, nThreads = gridDim.x * 256;
    const int gwave = blockIdx.x * 4 + wave,   nWaves = gridDim.x * 4;
    float part = 0.f;

    // Phase A: winner in {ja, jb}; exact compare with np first-index tie rule
    for (int i = gthread; i < nPair; i += nThreads) {
        int row = pairRows[i], jj = pairJJ[i];
        int ja = jj & 1023, jb = (jj >> 10) & 1023;
        if (ja > jb) { int t = ja; ja = jb; jb = t; }
        float xr[64];
        const f32x4* xp = (const f32x4*)(x + row * 64);
        #pragma unroll
        for (int t = 0; t < 16; ++t) {
            f32x4 v = xp[t];
            xr[4 * t] = v[0]; xr[4 * t + 1] = v[1]; xr[4 * t + 2] = v[2]; xr[4 * t + 3] = v[3];
        }
        float cr = np_norm64(xr);
        float da = exact_d(cr, se[ja], exact_dot64(xr, w + ja * 64));
        float db = exact_d(cr, se[jb], exact_dot64(xr, w + jb * 64));
        int win = (db < da) ? jb : ja;
        out[IDXOFF + row] = (float)win;
        const float* e = w + win * 64;
        {
            #pragma clang fp contract(off)
            #pragma unroll
            for (int i2 = 0; i2 < 64; ++i2) {
                float diff = e[i2] - xr[i2];
                part += diff * diff;
                out[QOFF + row * 64 + i2] = xr[i2] + diff;
            }
        }
    }

    // Phase B: full exact rescan, one row per wave.  Coalesced via wT; the 4-stripe
    // accumulator order (q = i&3, dims ascending) is bit-identical to exact_dot64.
    const f32x4* wT4 = (const f32x4*)wT;
    for (int i = gwave; i < nFull; i += nWaves) {
        int row = fullRows[i];
        float xr[64];                                    // same row for all lanes (broadcast)
        const f32x4* xp = (const f32x4*)(x + row * 64);
        #pragma unroll
        for (int t = 0; t < 16; ++t) {
            f32x4 v = xp[t];
            xr[4 * t] = v[0]; xr[4 * t + 1] = v[1]; xr[4 * t + 2] = v[2]; xr[4 * t + 3] = v[3];
        }
        float cr = np_norm64(xr);
        float bd = 3.402823466e38f; int bj = 0;
        #pragma unroll
        for (int g = 0; g < 4; ++g) {                    // pass g: codes g*256 + 4*lane + c
            f32x4 a0 = {0.f,0.f,0.f,0.f}, a1 = a0, a2 = a0, a3 = a0;
            #pragma unroll 4
            for (int i2 = 0; i2 < 64; i2 += 4) {
                f32x4 w0 = wT4[(i2 + 0) * 256 + g * 64 + lane];
                f32x4 w1 = wT4[(i2 + 1) * 256 + g * 64 + lane];
                f32x4 w2 = wT4[(i2 + 2) * 256 + g * 64 + lane];
                f32x4 w3 = wT4[(i2 + 3) * 256 + g * 64 + lane];
                #pragma unroll
                for (int c = 0; c < 4; ++c) {
                    a0[c] = fmaf(xr[i2 + 0], w0[c], a0[c]);
                    a1[c] = fmaf(xr[i2 + 1], w1[c], a1[c]);
                    a2[c] = fmaf(xr[i2 + 2], w2[c], a2[c]);
                    a3[c] = fmaf(xr[i2 + 3], w3[c], a3[c]);
                }
            }
            #pragma unroll
            for (int c = 0; c < 4; ++c) {
                float dot = (a0[c] + a1[c]) + (a2[c] + a3[c]);
                int j = g * 256 + lane * 4 + c;
                float d = exact_d(cr, se[j], dot);
                if (d < bd) { bd = d; bj = j; }          // per-lane j ascending => np tie rule
            }
        }
        for (int mask = 1; mask < 64; mask <<= 1) {
            float od = __shfl_xor(bd, mask, 64);
            int   oj = __shfl_xor(bj, mask, 64);
            if (od < bd || (od == bd && oj < bj)) { bd = od; bj = oj; }
        }
        {
            #pragma clang fp contract(off)
            float xv = x[row * 64 + lane];
            float wv = w[bj * 64 + lane];
            float diff = wv - xv;
            part += diff * diff;
            out[QOFF + row * 64 + lane] = xv + diff;
        }
        if (lane == 0) out[IDXOFF + row] = (float)bj;
    }

    for (int off = 32; off > 0; off >>= 1) part += __shfl_down(part, off, 64);
    if (lane == 0) sPart[wave] = part;
    __syncthreads();
    if (tid == 0) partial[NSCR + blockIdx.x] = (sPart[0] + sPart[1]) + (sPart[2] + sPart[3]);
}

// ---------- loss: single block sums the 2048 per-block partials, one writer ----------
__global__ __launch_bounds__(256) void vq_loss(const float* __restrict__ partial,
                                               float* __restrict__ out) {
    __shared__ float red[4];
    const int tid = threadIdx.x, lane = tid & 63, wave = tid >> 6;
    float s = 0.f;
    #pragma unroll
    for (int t = 0; t < 8; ++t) s += partial[t * 256 + tid];   // 8*256 = 2048 = NSCR+NFIN
    for (int off = 32; off > 0; off >>= 1) s += __shfl_down(s, off, 64);
    if (lane == 0) red[wave] = s;
    __syncthreads();
    if (tid == 0) out[0] = ((red[0] + red[1]) + (red[2] + red[3])) * (1.25f / 8388608.0f);
}

extern "C" void kernel_launch(void* const* d_in, const int* in_sizes, int n_in,
                              void* d_out, int out_size, void* d_ws, size_t ws_size,
                              hipStream_t stream) {
    const float* x = (const float*)d_in[0];
    const float* w = (const float*)d_in[1];
    float* out = (float*)d_out;

    unsigned short* Gf = (unsigned short*)d_ws;                  // 128 KB fragment-order fp16
    float* se   = (float*)((char*)d_ws + 131072);                // 4 KB
    float* se20 = (float*)((char*)d_ws + 135168);                // 4 KB
    float* wT   = (float*)((char*)d_ws + 139264);                // 256 KB column-major fp32
    int* gcnt   = (int*)((char*)d_ws + 401408);                  // 8 B (pad to 512)
    int* pairRows = (int*)((char*)d_ws + 401920);                // 512 KB worst case
    int* pairJJ   = pairRows + NROWS;                            // 512 KB
    int* fullRows = pairJJ + NROWS;                              // 512 KB
    float* partial = (float*)(fullRows + NROWS);                 // 8 KB (2048 floats)

    vq_prep<<<256, 256, 0, stream>>>(w, Gf, wT, se, se20, gcnt);
    vq_screen<<<NSCR, 256, 0, stream>>>(x, w, Gf, se20, out, partial, gcnt,
                                        pairRows, pairJJ, fullRows);
    vq_finish<<<NFIN, 256, 0, stream>>>(x, w, wT, se, out, partial, gcnt,
                                        pairRows, pairJJ, fullRows);
    vq_loss<<<1, 256, 0, stream>>>(partial, out);
}

// Round 13
// 169.526 us; speedup vs baseline: 1.1785x; 1.0289x over previous
//
#include <hip/hip_runtime.h>

#define NROWS   131072
#define DIM     64
#define K       1024
#define QOFF    1
#define IDXOFF  8388609        // 1 + NROWS*DIM
// Per-row routing margin in 2^-20 distance units: hard error of the fp16 screen
// is 2^-19 * sum|x_i| per distance => 2*S units.  mq = 2.002*S + 5 covers
// fp32 S-summation slack, MFMA fp32 accumulation (<=1), trunc quant (2), ceil (1).
#define NSCR    1024           // screen grid (128 rows/block, 4 blocks/CU)
#define NFIN    1024           // finish grid

typedef float    f32x4 __attribute__((ext_vector_type(4)));
typedef _Float16 f16x8 __attribute__((ext_vector_type(8)));

// exact sorted-triple insert step via v_med3_i32 (3 VALU ops instead of 5):
// m3' = med3(m2,m3,k); m2' = med3(m1,m2,k); m1' = min(m1,k).
__device__ __forceinline__ int med3_i32(int a, int b, int c) {
    int d;
    asm("v_med3_i32 %0, %1, %2, %3" : "=v"(d) : "v"(a), "v"(b), "v"(c));
    return d;
}

// ---------- np-exact arithmetic (validated: absmax 0.0) ----------
__device__ __forceinline__ float np_norm64(const float* v) {
    #pragma clang fp contract(off)
    float r[8];
    #pragma unroll
    for (int k = 0; k < 8; ++k) r[k] = v[k] * v[k];
    #pragma unroll
    for (int i = 8; i < 64; i += 8)
        #pragma unroll
        for (int k = 0; k < 8; ++k) r[k] += v[i + k] * v[i + k];
    return ((r[0] + r[1]) + (r[2] + r[3])) + ((r[4] + r[5]) + (r[6] + r[7]));
}
__device__ __forceinline__ float exact_dot64(const float* __restrict__ xr,
                                             const float* __restrict__ e) {
    float a0 = 0.f, a1 = 0.f, a2 = 0.f, a3 = 0.f;
    #pragma unroll
    for (int i = 0; i < 64; i += 4) {
        a0 = fmaf(xr[i + 0], e[i + 0], a0);
        a1 = fmaf(xr[i + 1], e[i + 1], a1);
        a2 = fmaf(xr[i + 2], e[i + 2], a2);
        a3 = fmaf(xr[i + 3], e[i + 3], a3);
    }
    return (a0 + a1) + (a2 + a3);
}
__device__ __forceinline__ float exact_d(float cr, float sej, float dot) {
    #pragma clang fp contract(off)
    float t = cr + sej;
    return t - 2.0f * dot;
}

// ---------- prep v2: 256 blocks.  Transpose 1 elem/thread; Gf on blocks 0..31;
// se on blocks 32..63 via 8-lane stripe+xor-tree (bit-identical to np_norm64) ----------
__global__ __launch_bounds__(256) void vq_prep(
    const float* __restrict__ w, unsigned short* __restrict__ Gf,
    float* __restrict__ wT, float* __restrict__ se, float* __restrict__ se20,
    int* __restrict__ gcnt) {
    const int b = blockIdx.x, t = threadIdx.x;
    const int g = b * 256 + t;                       // 0..65535
    if (g < 2) gcnt[g] = 0;
    // transpose: wT[i*1024 + j] = w[j*64 + i]  (coalesced write, 1 elem/thread)
    wT[g] = w[(g & 1023) * 64 + (g >> 10)];
    if (b < 32) {
        // Gf fragment-order fp16: gid = ntile*128 + c*64 + lane
        int gid = g;
        int lane = gid & 63, c = (gid >> 6) & 1, ntile = gid >> 7;
        int code = ntile * 16 + (lane & 15);
        int k0 = c * 32 + (lane >> 4) * 8;
        const float* rowp = w + code * 64 + k0;
        f16x8 h8;
        #pragma unroll
        for (int j = 0; j < 8; ++j) h8[j] = (_Float16)(rowp[j] * 1024.0f);  // *1024 exact
        *(f16x8*)(Gf + gid * 8) = h8;
    } else if (b < 64) {
        // se: 8 codes per wave, 8 lanes per code; stripe st accumulates r[st] then
        // xor-tree 1/2/4 reproduces ((r0+r1)+(r2+r3))+((r4+r5)+(r6+r7)) exactly.
        #pragma clang fp contract(off)
        int wv = (b - 32) * 4 + (t >> 6);            // 0..127
        int k = t & 63;
        int code = wv * 8 + (k >> 3), st = k & 7;
        const float* e = w + code * 64 + st;
        float r = 0.f;
        #pragma unroll
        for (int i = 0; i < 8; ++i) { float v = e[8 * i]; r += v * v; }  // 0+v0*v0 exact
        r += __shfl_xor(r, 1, 64);
        r += __shfl_xor(r, 2, 64);
        r += __shfl_xor(r, 4, 64);
        if (st == 0) { se[code] = r; se20[code] = r * 1048576.0f; }
    }
}

// ---------- screen: fp16 MFMA scan, depth-4 B prefetch, med3-based top-3 ----------
// block = 256 (4 waves); TWO 16-row m-tiles per wave (32 rows); grid = 1024 (4 blocks/CU).
__global__ __launch_bounds__(256, 4) void vq_screen(
    const float* __restrict__ x, const float* __restrict__ w,
    const unsigned short* __restrict__ Gf, const float* __restrict__ se20,
    float* __restrict__ out, float* __restrict__ partial, int* __restrict__ gcnt,
    int* __restrict__ pairRows, int* __restrict__ pairJJ, int* __restrict__ fullRows) {
    __shared__ float sSe[1024];         // 4 KB: se*2^20
    __shared__ float sPart[4];
    __shared__ int sCnt[2], sBase[2];
    __shared__ int sPairRow[128], sPairJJ[128], sFullRow[128];
    const int tid  = threadIdx.x;
    const int wave = tid >> 6, lane = tid & 63;
    const int quad = lane >> 4, m16 = lane & 15;
    const int wrow0 = blockIdx.x * 128 + wave * 32;

    if (tid < 2) sCnt[tid] = 0;
    #pragma unroll
    for (int t = 0; t < 4; ++t) sSe[t * 256 + tid] = se20[t * 256 + tid];

    // A fragments: fp16(x), A[m = m16][k = quad*8 + j], chunk c: k = 32c..32c+31
    f16x8 Ah[2][2];
    float Sloc[2] = {0.f, 0.f};
    #pragma unroll
    for (int mt = 0; mt < 2; ++mt)
        #pragma unroll
        for (int c = 0; c < 2; ++c) {
            const float* p = x + (wrow0 + mt * 16 + m16) * 64 + c * 32 + quad * 8;
            f32x4 u0 = *(const f32x4*)p;
            f32x4 u1 = *(const f32x4*)(p + 4);
            #pragma unroll
            for (int j = 0; j < 8; ++j) {
                float xv = (j < 4) ? u0[j] : u1[j - 4];
                Ah[mt][c][j] = (_Float16)xv;
                Sloc[mt] += fabsf(xv);
            }
        }
    #pragma unroll
    for (int mt = 0; mt < 2; ++mt) {
        Sloc[mt] += __shfl_xor(Sloc[mt], 16, 64);
        Sloc[mt] += __shfl_xor(Sloc[mt], 32, 64);   // every lane: S(row = its m16)
    }

    int m1[2][4], m2[2][4], m3[2][4];
    #pragma unroll
    for (int mt = 0; mt < 2; ++mt)
        #pragma unroll
        for (int r = 0; r < 4; ++r) {
            m1[mt][r] = 0x7fffffff; m2[mt][r] = 0x7fffffff; m3[mt][r] = 0x7fffffff;
        }

    // prime the 4-slot B prefetch ring (tiles 0..3)
    f16x8 pb0[4], pb1[4];
    #pragma unroll
    for (int i = 0; i < 4; ++i) {
        pb0[i] = *(const f16x8*)(Gf + i * 1024 + lane * 8);
        pb1[i] = *(const f16x8*)(Gf + i * 1024 + 512 + lane * 8);
    }

    __syncthreads();                    // sSe + sCnt ready

    for (int tt = 0; tt < 64; tt += 8) {
        #pragma unroll
        for (int k = 0; k < 8; ++k) {
            const int t = tt + k;
            const int s = k & 3;                         // == t & 3 (tt % 8 == 0)
            f16x8 B0 = pb0[s], B1 = pb1[s];
            int tn = t + 4; tn = (tn > 63) ? 63 : tn;    // clamped (redundant tail loads ok)
            pb0[s] = *(const f16x8*)(Gf + tn * 1024 + lane * 8);
            pb1[s] = *(const f16x8*)(Gf + tn * 1024 + 512 + lane * 8);
            float sen = sSe[t * 16 + m16];
            int jn = t * 16 + m16;
            #pragma unroll
            for (int mt = 0; mt < 2; ++mt) {
                f32x4 acc = {0.f, 0.f, 0.f, 0.f};
                acc = __builtin_amdgcn_mfma_f32_16x16x32_f16(Ah[mt][0], B0, acc, 0, 0, 0);
                acc = __builtin_amdgcn_mfma_f32_16x16x32_f16(Ah[mt][1], B1, acc, 0, 0, 0);
                #pragma unroll
                for (int r = 0; r < 4; ++r) {
                    // f*2^20 = se*2^20 - 2*2^-10*2^20*dot' ; dot' = 1024*x.e
                    float kf = fmaf(acc[r], -2048.0f, sen);
                    int q = (int)kf;                              // trunc: monotone
                    int key = (int)((unsigned)q << 10) | jn;
                    int nm3 = med3_i32(m2[mt][r], m3[mt][r], key); // exact sorted-3 insert
                    int nm2 = med3_i32(m1[mt][r], m2[mt][r], key);
                    m3[mt][r] = nm3;
                    m2[mt][r] = nm2;
                    m1[mt][r] = min(m1[mt][r], key);
                }
            }
        }
    }

    // butterfly all-reduce top-3 over the 16 cols (C layout: col=m16, row=quad*4+r)
    #pragma unroll
    for (int mask = 1; mask <= 8; mask <<= 1) {
        #pragma unroll
        for (int mt = 0; mt < 2; ++mt)
            #pragma unroll
            for (int r = 0; r < 4; ++r) {
                int b1 = __shfl_xor(m1[mt][r], mask, 64);
                int b2 = __shfl_xor(m2[mt][r], mask, 64);
                int b3 = __shfl_xor(m3[mt][r], mask, 64);
                int lo1 = min(m1[mt][r], b1), hi1 = max(m1[mt][r], b1);
                int lo2 = min(m2[mt][r], b2);
                m1[mt][r] = lo1;
                m2[mt][r] = min(hi1, lo2);
                m3[mt][r] = min(max(hi1, lo2), min(m3[mt][r], b3));
            }
    }

    int jd[2][4];                       // decided winner (or -1) per mt, row quad*4+r
    #pragma unroll
    for (int mt = 0; mt < 2; ++mt)
        #pragma unroll
        for (int r = 0; r < 4; ++r) {
            int k1 = m1[mt][r], k2 = m2[mt][r], k3 = m3[mt][r];
            int g21 = (k2 >> 10) - (k1 >> 10);
            int g31 = (k3 >> 10) - (k1 >> 10);
            int j1 = k1 & 1023;
            float Srow = __shfl(Sloc[mt], quad * 4 + r, 64);   // S of row quad*4+r
            int mq = (int)(Srow * 2.002f) + 5;                 // per-row hard margin
            jd[mt][r] = (g21 > mq) ? j1 : -1;
            if (m16 == 0) {
                int rowG = wrow0 + mt * 16 + quad * 4 + r;
                if (g21 > mq) {
                    out[IDXOFF + rowG] = (float)j1;
                } else if (g31 > mq) {                         // winner in {j1, j2}
                    int p = atomicAdd(&sCnt[0], 1);
                    sPairRow[p] = rowG; sPairJJ[p] = j1 | ((k2 & 1023) << 10);
                } else {                                       // rare: full rescan
                    int p = atomicAdd(&sCnt[1], 1);
                    sFullRow[p] = rowG;
                }
            }
        }

    // q_st + loss for decided rows, coalesced: lane = dim; winner broadcast via static shfl
    float part = 0.f;
    #pragma unroll
    for (int i = 0; i < 32; ++i) {      // row i = mt(i>>4)*16 + quad((i&15)>>2)*4 + r(i&3)
        int jr = __shfl(jd[i >> 4][i & 3], ((i & 15) >> 2) * 16, 64);
        if (jr >= 0) {
            #pragma clang fp contract(off)
            int rowG = wrow0 + i;
            float xv = x[rowG * 64 + lane];
            float wv = w[jr * 64 + lane];
            float diff = wv - xv;
            part += diff * diff;
            out[QOFF + rowG * 64 + lane] = xv + diff;
        }
    }
    for (int off = 32; off > 0; off >>= 1) part += __shfl_down(part, off, 64);
    if (lane == 0) sPart[wave] = part;
    __syncthreads();                    // sPart + LDS lists + sCnt final
    if (tid == 0) {
        partial[blockIdx.x] = (sPart[0] + sPart[1]) + (sPart[2] + sPart[3]);
        int np_ = sCnt[0], nf = sCnt[1];
        sBase[0] = np_ ? atomicAdd(&gcnt[0], np_) : 0;     // one atomic per block/category
        sBase[1] = nf  ? atomicAdd(&gcnt[1], nf)  : 0;
    }
    __syncthreads();                    // sBase ready
    if (tid < sCnt[0]) {
        int d = sBase[0] + tid;
        pairRows[d] = sPairRow[tid]; pairJJ[d] = sPairJJ[tid];
    }
    if (tid < sCnt[1]) fullRows[sBase[1] + tid] = sFullRow[tid];
}

// ---------- finish: dense lists; exact pair-compares (thread) + coalesced full rescans ----
__global__ __launch_bounds__(256) void vq_finish(
    const float* __restrict__ x, const float* __restrict__ w, const float* __restrict__ wT,
    const float* __restrict__ se, float* __restrict__ out, float* __restrict__ partial,
    const int* __restrict__ gcnt, const int* __restrict__ pairRows,
    const int* __restrict__ pairJJ, const int* __restrict__ fullRows) {
    __shared__ float sPart[4];
    const int tid = threadIdx.x;
    const int lane = tid & 63, wave = tid >> 6;
    const int nPair = gcnt[0], nFull = gcnt[1];
    const int gthread = blockIdx.x * 256 + tid, nThreads = gridDim.x * 256;
    const int gwave = blockIdx.x * 4 + wave,   nWaves = gridDim.x * 4;
    float part = 0.f;

    // Phase A: winner in {ja, jb}; exact compare with np first-index tie rule
    for (int i = gthread; i < nPair; i += nThreads) {
        int row = pairRows[i], jj = pairJJ[i];
        int ja = jj & 1023, jb = (jj >> 10) & 1023;
        if (ja > jb) { int t = ja; ja = jb; jb = t; }
        float xr[64];
        const f32x4* xp = (const f32x4*)(x + row * 64);
        #pragma unroll
        for (int t = 0; t < 16; ++t) {
            f32x4 v = xp[t];
            xr[4 * t] = v[0]; xr[4 * t + 1] = v[1]; xr[4 * t + 2] = v[2]; xr[4 * t + 3] = v[3];
        }
        float cr = np_norm64(xr);
        float da = exact_d(cr, se[ja], exact_dot64(xr, w + ja * 64));
        float db = exact_d(cr, se[jb], exact_dot64(xr, w + jb * 64));
        int win = (db < da) ? jb : ja;
        out[IDXOFF + row] = (float)win;
        const float* e = w + win * 64;
        {
            #pragma clang fp contract(off)
            #pragma unroll
            for (int i2 = 0; i2 < 64; ++i2) {
                float diff = e[i2] - xr[i2];
                part += diff * diff;
                out[QOFF + row * 64 + i2] = xr[i2] + diff;
            }
        }
    }

    // Phase B: full exact rescan, one row per wave.  Coalesced via wT; the 4-stripe
    // accumulator order (q = i&3, dims ascending) is bit-identical to exact_dot64.
    const f32x4* wT4 = (const f32x4*)wT;
    for (int i = gwave; i < nFull; i += nWaves) {
        int row = fullRows[i];
        float xr[64];                                    // same row for all lanes (broadcast)
        const f32x4* xp = (const f32x4*)(x + row * 64);
        #pragma unroll
        for (int t = 0; t < 16; ++t) {
            f32x4 v = xp[t];
            xr[4 * t] = v[0]; xr[4 * t + 1] = v[1]; xr[4 * t + 2] = v[2]; xr[4 * t + 3] = v[3];
        }
        float cr = np_norm64(xr);
        float bd = 3.402823466e38f; int bj = 0;
        #pragma unroll
        for (int g = 0; g < 4; ++g) {                    // pass g: codes g*256 + 4*lane + c
            f32x4 a0 = {0.f,0.f,0.f,0.f}, a1 = a0, a2 = a0, a3 = a0;
            #pragma unroll 4
            for (int i2 = 0; i2 < 64; i2 += 4) {
                f32x4 w0 = wT4[(i2 + 0) * 256 + g * 64 + lane];
                f32x4 w1 = wT4[(i2 + 1) * 256 + g * 64 + lane];
                f32x4 w2 = wT4[(i2 + 2) * 256 + g * 64 + lane];
                f32x4 w3 = wT4[(i2 + 3) * 256 + g * 64 + lane];
                #pragma unroll
                for (int c = 0; c < 4; ++c) {
                    a0[c] = fmaf(xr[i2 + 0], w0[c], a0[c]);
                    a1[c] = fmaf(xr[i2 + 1], w1[c], a1[c]);
                    a2[c] = fmaf(xr[i2 + 2], w2[c], a2[c]);
                    a3[c] = fmaf(xr[i2 + 3], w3[c], a3[c]);
                }
            }
            #pragma unroll
            for (int c = 0; c < 4; ++c) {
                float dot = (a0[c] + a1[c]) + (a2[c] + a3[c]);
                int j = g * 256 + lane * 4 + c;
                float d = exact_d(cr, se[j], dot);
                if (d < bd) { bd = d; bj = j; }          // per-lane j ascending => np tie rule
            }
        }
        for (int mask = 1; mask < 64; mask <<= 1) {
            float od = __shfl_xor(bd, mask, 64);
            int   oj = __shfl_xor(bj, mask, 64);
            if (od < bd || (od == bd && oj < bj)) { bd = od; bj = oj; }
        }
        {
            #pragma clang fp contract(off)
            float xv = x[row * 64 + lane];
            float wv = w[bj * 64 + lane];
            float diff = wv - xv;
            part += diff * diff;
            out[QOFF + row * 64 + lane] = xv + diff;
        }
        if (lane == 0) out[IDXOFF + row] = (float)bj;
    }

    for (int off = 32; off > 0; off >>= 1) part += __shfl_down(part, off, 64);
    if (lane == 0) sPart[wave] = part;
    __syncthreads();
    if (tid == 0) partial[NSCR + blockIdx.x] = (sPart[0] + sPart[1]) + (sPart[2] + sPart[3]);
}

// ---------- loss: single block sums the 2048 per-block partials, one writer ----------
__global__ __launch_bounds__(256) void vq_loss(const float* __restrict__ partial,
                                               float* __restrict__ out) {
    __shared__ float red[4];
    const int tid = threadIdx.x, lane = tid & 63, wave = tid >> 6;
    float s = 0.f;
    #pragma unroll
    for (int t = 0; t < 8; ++t) s += partial[t * 256 + tid];   // 8*256 = 2048 = NSCR+NFIN
    for (int off = 32; off > 0; off >>= 1) s += __shfl_down(s, off, 64);
    if (lane == 0) red[wave] = s;
    __syncthreads();
    if (tid == 0) out[0] = ((red[0] + red[1]) + (red[2] + red[3])) * (1.25f / 8388608.0f);
}

extern "C" void kernel_launch(void* const* d_in, const int* in_sizes, int n_in,
                              void* d_out, int out_size, void* d_ws, size_t ws_size,
                              hipStream_t stream) {
    const float* x = (const float*)d_in[0];
    const float* w = (const float*)d_in[1];
    float* out = (float*)d_out;

    unsigned short* Gf = (unsigned short*)d_ws;                  // 128 KB fragment-order fp16
    float* se   = (float*)((char*)d_ws + 131072);                // 4 KB
    float* se20 = (float*)((char*)d_ws + 135168);                // 4 KB
    float* wT   = (float*)((char*)d_ws + 139264);                // 256 KB column-major fp32
    int* gcnt   = (int*)((char*)d_ws + 401408);                  // 8 B (pad to 512)
    int* pairRows = (int*)((char*)d_ws + 401920);                // 512 KB worst case
    int* pairJJ   = pairRows + NROWS;                            // 512 KB
    int* fullRows = pairJJ + NROWS;                              // 512 KB
    float* partial = (float*)(fullRows + NROWS);                 // 8 KB (2048 floats)

    vq_prep<<<256, 256, 0, stream>>>(w, Gf, wT, se, se20, gcnt);
    vq_screen<<<NSCR, 256, 0, stream>>>(x, w, Gf, se20, out, partial, gcnt,
                                        pairRows, pairJJ, fullRows);
    vq_finish<<<NFIN, 256, 0, stream>>>(x, w, wT, se, out, partial, gcnt,
                                        pairRows, pairJJ, fullRows);
    vq_loss<<<1, 256, 0, stream>>>(partial, out);
}